// Round 1
// baseline (211.762 us; speedup 1.0000x reference)
//
#include <hip/hip_runtime.h>

#define NB 16   // batch
#define NN 512  // input capsules (n)
#define DI 256  // input dim (i)
#define NC 64   // output capsules (c)
#define ND 128  // capsule dim (d)
#define FO 8192 // NC*ND

// ---------------------------------------------------------------------------
// Stage 1: column sums of x  (deterministic two-stage, no atomics)
// part[b][s][i] = sum_{n in s-th chunk of 32} x[b][n][i]
__global__ __launch_bounds__(256) void k_part(const float* __restrict__ x,
                                              float* __restrict__ part) {
  int b = blockIdx.x, s = blockIdx.y, i = threadIdx.x;
  const float* xp = x + (b * NN + s * 32) * DI + i;
  float acc = 0.f;
#pragma unroll 8
  for (int n = 0; n < 32; ++n) acc += xp[n * DI];
  part[(b * 16 + s) * DI + i] = acc;
}

// xsum[b][i] = sum_s part[b][s][i]
__global__ __launch_bounds__(256) void k_xsum(const float* __restrict__ part,
                                              float* __restrict__ xsum) {
  int b = blockIdx.x, i = threadIdx.x;
  float acc = 0.f;
#pragma unroll
  for (int s = 0; s < 16; ++s) acc += part[(b * 16 + s) * DI + i];
  xsum[b * DI + i] = acc;
}

// ---------------------------------------------------------------------------
// o-compute + squash (+ w-compute) per (b,c) block.  128 threads = 2 waves.
//   o_raw[d] = sum_i y[b,c,i] * K[i, c*128+d];  o = squash(o_raw)
//   w[b,c,i] = sum_d o[d] * K[i, c*128+d]        (if CALC_W)
template <bool FIRST, bool CALC_W, bool TO_OUT>
__global__ __launch_bounds__(128) void k_o(const float* __restrict__ kern,
                                           const float* __restrict__ yb,
                                           const float* __restrict__ xsum,
                                           float* __restrict__ wout,
                                           float* __restrict__ outp) {
  int bc = blockIdx.x;
  int b = bc >> 6, c = bc & 63;
  int d = threadIdx.x;           // 0..127
  int wid = d >> 6, lane = d & 63;

  __shared__ float y_lds[DI];
  __shared__ float o_lds[ND];
  __shared__ float red[2];

  if (FIRST) {
    y_lds[d]       = xsum[b * DI + d]       * (1.f / 64.f);
    y_lds[d + 128] = xsum[b * DI + d + 128] * (1.f / 64.f);
  } else {
    y_lds[d]       = yb[bc * DI + d];
    y_lds[d + 128] = yb[bc * DI + d + 128];
  }
  __syncthreads();

  const float* kp = kern + c * ND + d;
  float acc = 0.f;
#pragma unroll 8
  for (int i = 0; i < DI; ++i) acc += y_lds[i] * kp[(size_t)i * FO];

  // squash: sq_norm over d (128 values, 2 waves)
  float sq = acc * acc;
#pragma unroll
  for (int off = 32; off >= 1; off >>= 1) sq += __shfl_xor(sq, off, 64);
  if (lane == 0) red[wid] = sq;
  __syncthreads();
  float tot = red[0] + red[1] + 1e-7f;
  float scale = sqrtf(tot) / (0.5f + tot);
  float ov = scale * acc;

  if (TO_OUT) outp[bc * ND + d] = ov;

  if (CALC_W) {
    o_lds[d] = ov;
    __syncthreads();
    float o1 = o_lds[lane], o2 = o_lds[lane + 64];
    // each wave handles 128 i's; dot over d via lane-cooperative reduce
    for (int ii = 0; ii < 128; ++ii) {
      int i = wid * 128 + ii;
      const float* kr = kern + (size_t)i * FO + c * ND;
      float p = o1 * kr[lane] + o2 * kr[lane + 64];
#pragma unroll
      for (int off = 32; off >= 1; off >>= 1) p += __shfl_xor(p, off, 64);
      if (lane == 0) wout[bc * DI + i] = p;
    }
  }
}

// ---------------------------------------------------------------------------
// routing update: b_new[b,c,n] = (ADD_B ? b_old : 0) + sum_i x[b,n,i]*w[b,c,i]
// then softmax over c -> coef[b][n][c]; store b_new -> blog[b][n][c].
// Block: (b, 32-n chunk). 256 threads = 4 waves; lane = c; wave handles 8 n.
// w staged in LDS as [i][c ^ (i&63)]  (64 KB, conflict-free both sides).
template <bool ADD_B>
__global__ __launch_bounds__(256) void k_route(const float* __restrict__ x,
                                               const float* __restrict__ w,
                                               float* __restrict__ blog,
                                               float* __restrict__ coef) {
  int b = blockIdx.x;
  int n0 = blockIdx.y * 32;
  int tid = threadIdx.x;
  int wid = tid >> 6, lane = tid & 63;  // lane = capsule c

  __shared__ float w_lds[DI * NC];  // exactly 64 KB

  // stage w[b][c][i] -> w_lds[i*64 + (c ^ (i&63))]
  const float* wb = w + b * (NC * DI);
  for (int idx = tid; idx < NC * DI; idx += 256) {
    int c = idx >> 8, i = idx & 255;
    w_lds[i * 64 + (c ^ (i & 63))] = wb[idx];
  }
  __syncthreads();

  float acc[8];
#pragma unroll
  for (int k = 0; k < 8; ++k) acc[k] = 0.f;

  // 4 chunks of 64 i's: hold w-chunk in registers, stream x as float4 bcast
#pragma unroll 1
  for (int chunk = 0; chunk < 4; ++chunk) {
    int i0 = chunk * 64;
    float wreg[64];
#pragma unroll
    for (int j = 0; j < 64; ++j)
      wreg[j] = w_lds[(i0 + j) * 64 + (lane ^ j)];

#pragma unroll
    for (int k = 0; k < 8; ++k) {
      int n = n0 + wid * 8 + k;
      const float4* xp = (const float4*)(x + (b * NN + n) * DI + i0);
#pragma unroll
      for (int q = 0; q < 16; ++q) {
        float4 xv = xp[q];
        acc[k] += xv.x * wreg[q * 4 + 0] + xv.y * wreg[q * 4 + 1] +
                  xv.z * wreg[q * 4 + 2] + xv.w * wreg[q * 4 + 3];
      }
    }
  }

  // add old logits, store, softmax over c (= lanes of this wave)
#pragma unroll 1
  for (int k = 0; k < 8; ++k) {
    int n = n0 + wid * 8 + k;
    float v = acc[k];
    if (ADD_B) v += blog[(b * NN + n) * NC + lane];
    blog[(b * NN + n) * NC + lane] = v;
    float m = v;
#pragma unroll
    for (int off = 32; off >= 1; off >>= 1) m = fmaxf(m, __shfl_xor(m, off, 64));
    float e = __expf(v - m);
    float s = e;
#pragma unroll
    for (int off = 32; off >= 1; off >>= 1) s += __shfl_xor(s, off, 64);
    coef[(b * NN + n) * NC + lane] = e / s;
  }
}

// ---------------------------------------------------------------------------
// y[b,c,i] = sum_n coef[b][n][c] * x[b][n][i].  Block: (b, 4-c group).
__global__ __launch_bounds__(256) void k_y(const float* __restrict__ x,
                                           const float* __restrict__ coef,
                                           float* __restrict__ y) {
  int b = blockIdx.x;
  int c0 = blockIdx.y * 4;
  int i = threadIdx.x;
  const float* xb = x + b * NN * DI;
  const float* cb = coef + b * NN * NC + c0;
  float a0 = 0.f, a1 = 0.f, a2 = 0.f, a3 = 0.f;
#pragma unroll 4
  for (int n = 0; n < NN; ++n) {
    float xv = xb[n * DI + i];
    float c0v = cb[n * NC + 0];
    float c1v = cb[n * NC + 1];
    float c2v = cb[n * NC + 2];
    float c3v = cb[n * NC + 3];
    a0 += xv * c0v; a1 += xv * c1v; a2 += xv * c2v; a3 += xv * c3v;
  }
  y[((b * NC) + c0 + 0) * DI + i] = a0;
  y[((b * NC) + c0 + 1) * DI + i] = a1;
  y[((b * NC) + c0 + 2) * DI + i] = a2;
  y[((b * NC) + c0 + 3) * DI + i] = a3;
}

// ---------------------------------------------------------------------------
extern "C" void kernel_launch(void* const* d_in, const int* in_sizes, int n_in,
                              void* d_out, int out_size, void* d_ws, size_t ws_size,
                              hipStream_t stream) {
  (void)in_sizes; (void)n_in; (void)out_size; (void)ws_size;
  const float* x    = (const float*)d_in[0];   // [16,512,256]
  const float* kern = (const float*)d_in[1];   // [256,8192]
  float* out = (float*)d_out;                  // [16,64,128]

  float* part = (float*)d_ws;                  // 16*16*256   = 65536 f
  float* xsum = part + NB * 16 * DI;           // 16*256      = 4096 f
  float* y    = xsum + NB * DI;                // 16*64*256   = 262144 f
  float* w    = y + NB * NC * DI;              // 16*64*256   = 262144 f
  float* blog = w + NB * NC * DI;              // 16*512*64   = 524288 f
  float* coef = blog + NB * NN * NC;           // 16*512*64   = 524288 f

  // column sums of x (for uniform-coefficient iteration 0)
  k_part<<<dim3(NB, 16), 256, 0, stream>>>(x, part);
  k_xsum<<<NB, 256, 0, stream>>>(part, xsum);

  // iteration 0: c uniform = 1/64 -> o0, w0
  k_o<true, true, false><<<NB * NC, 128, 0, stream>>>(kern, y, xsum, w, out);
  // b1 = x.w0 ; softmax -> coef1
  k_route<false><<<dim3(NB, 16), 256, 0, stream>>>(x, w, blog, coef);

  // iteration 1
  k_y<<<dim3(NB, 16), 256, 0, stream>>>(x, coef, y);
  k_o<false, true, false><<<NB * NC, 128, 0, stream>>>(kern, y, xsum, w, out);
  // b2 = b1 + x.w1 ; softmax -> coef2
  k_route<true><<<dim3(NB, 16), 256, 0, stream>>>(x, w, blog, coef);

  // iteration 2 (final): o2 -> out
  k_y<<<dim3(NB, 16), 256, 0, stream>>>(x, coef, y);
  k_o<false, false, true><<<NB * NC, 128, 0, stream>>>(kern, y, xsum, w, out);
}

// Round 2
// 135.949 us; speedup vs baseline: 1.5577x; 1.5577x over previous
//
#include <hip/hip_runtime.h>

#define NB 16   // batch
#define NN 512  // input capsules (n)
#define DI 256  // input dim (i)
#define NC 64   // output capsules (c)
#define ND 128  // capsule dim (d)
#define FO 8192 // NC*DC

// ---------------------------------------------------------------------------
// Stage 1: column sums of x  (deterministic two-stage, no atomics)
__global__ __launch_bounds__(256) void k_part(const float* __restrict__ x,
                                              float* __restrict__ part) {
  int b = blockIdx.x, s = blockIdx.y, i = threadIdx.x;
  const float* xp = x + (b * NN + s * 32) * DI + i;
  float acc = 0.f;
#pragma unroll 8
  for (int n = 0; n < 32; ++n) acc += xp[n * DI];
  part[(b * 16 + s) * DI + i] = acc;
}

__global__ __launch_bounds__(256) void k_xsum(const float* __restrict__ part,
                                              float* __restrict__ xsum) {
  int b = blockIdx.x, i = threadIdx.x;
  float acc = 0.f;
#pragma unroll
  for (int s = 0; s < 16; ++s) acc += part[(b * 16 + s) * DI + i];
  xsum[b * DI + i] = acc;
}

// ---------------------------------------------------------------------------
// k_o2: per block = (c, half-of-batch). Computes for 8 b's:
//   O_raw[8,128] = Y[8,256] . Kc[256,128]   (Kc = kern[:, c*128 : c*128+128])
//   O = squash(O_raw)  (norm over d per row)
//   W[8,256] = O[8,128] . Kc^T              (if CALC_W)
// 256 threads = 4 waves. K-slice read once per phase, coalesced float4.
template <bool FIRST, bool CALC_W, bool TO_OUT>
__global__ __launch_bounds__(256) void k_o2(const float* __restrict__ kern,
                                            const float* __restrict__ yb,
                                            const float* __restrict__ xsum,
                                            float* __restrict__ wout,
                                            float* __restrict__ outp) {
  int c = blockIdx.x;        // 0..63
  int b0 = blockIdx.y * 8;   // 0 or 8
  int tid = threadIdx.x;

  __shared__ float y_lds[8][256];   // 8 KB
  __shared__ float u_lds[8192];     // 32 KB: phase1 partials p[8][8][128]; phase2 kt[32][132]
  __shared__ float o_lds[8][128];   // 4 KB

  // ---- load Y (8 rows x 256) as float4
#pragma unroll
  for (int k = 0; k < 2; ++k) {
    int e4 = tid + k * 256;          // 0..511 (512 float4 total)
    int bb = e4 >> 6, i4 = e4 & 63;
    float4 v;
    if (FIRST) {
      v = ((const float4*)xsum)[(b0 + bb) * 64 + i4];
      v.x *= (1.f / 64.f); v.y *= (1.f / 64.f); v.z *= (1.f / 64.f); v.w *= (1.f / 64.f);
    } else {
      v = ((const float4*)yb)[((b0 + bb) * 64 + c) * 64 + i4];
    }
    ((float4*)&y_lds[bb][0])[i4] = v;
  }
  __syncthreads();

  // ---- phase 1: partial O_raw. thread = (i-range half 0..7, d-quad 0..31)
  {
    int dq = tid & 31;
    int half = tid >> 5;
    float4 acc[8];
#pragma unroll
    for (int bb = 0; bb < 8; ++bb) { acc[bb].x = acc[bb].y = acc[bb].z = acc[bb].w = 0.f; }
    const float* kp = kern + c * ND + dq * 4;
#pragma unroll 4
    for (int t = 0; t < 32; ++t) {
      int i = half * 32 + t;
      float4 kv = *(const float4*)(kp + (size_t)i * FO);
#pragma unroll
      for (int bb = 0; bb < 8; ++bb) {
        float yv = y_lds[bb][i];
        acc[bb].x += yv * kv.x; acc[bb].y += yv * kv.y;
        acc[bb].z += yv * kv.z; acc[bb].w += yv * kv.w;
      }
    }
    float4* p4 = (float4*)u_lds;     // p[half][bb][32 dq]
#pragma unroll
    for (int bb = 0; bb < 8; ++bb) p4[(half * 8 + bb) * 32 + dq] = acc[bb];
  }
  __syncthreads();

  // ---- combine partials + squash. thread = (bb 0..7, j 0..31), d = j*4..j*4+3
  {
    int bb = tid >> 5, j = tid & 31;
    const float4* p4 = (const float4*)u_lds;
    float4 o; o.x = o.y = o.z = o.w = 0.f;
#pragma unroll
    for (int h = 0; h < 8; ++h) {
      float4 p = p4[(h * 8 + bb) * 32 + j];
      o.x += p.x; o.y += p.y; o.z += p.z; o.w += p.w;
    }
    float sq = o.x * o.x + o.y * o.y + o.z * o.z + o.w * o.w;
#pragma unroll
    for (int off = 16; off >= 1; off >>= 1) sq += __shfl_xor(sq, off, 64);
    float tot = sq + 1e-7f;
    float scale = sqrtf(tot) / (0.5f + tot);
    o.x *= scale; o.y *= scale; o.z *= scale; o.w *= scale;
    ((float4*)&o_lds[bb][0])[j] = o;
    if (TO_OUT) ((float4*)outp)[((b0 + bb) * NC + c) * 32 + j] = o;
  }
  __syncthreads();

  // ---- phase 2: W[8,256] = O . Kc^T, i-tiles of 32 staged in LDS
  if (CALC_W) {
    float* kt = u_lds;   // [32][132]
    int bb = tid >> 5, ii = tid & 31;
    const float4* o4 = (const float4*)&o_lds[bb][0];
#pragma unroll 1
    for (int i0 = 0; i0 < DI; i0 += 32) {
      // stage 32x128 floats, coalesced float4
#pragma unroll
      for (int k = 0; k < 4; ++k) {
        int e4 = tid + k * 256;        // 0..1023
        int r = e4 >> 5, q = e4 & 31;
        float4 v = *(const float4*)(kern + (size_t)(i0 + r) * FO + c * ND + q * 4);
        *(float4*)(kt + r * 132 + q * 4) = v;
      }
      __syncthreads();
      float wacc = 0.f;
#pragma unroll 8
      for (int q = 0; q < 32; ++q) {
        float4 kv = *(const float4*)(kt + ii * 132 + q * 4);
        float4 ov = o4[q];
        wacc += kv.x * ov.x + kv.y * ov.y + kv.z * ov.z + kv.w * ov.w;
      }
      wout[((b0 + bb) * NC + c) * DI + i0 + ii] = wacc;
      __syncthreads();
    }
  }
}

// ---------------------------------------------------------------------------
// routing update: b_new[b,c,n] = (ADD_B ? b_old : 0) + sum_i x[b,n,i]*w[b,c,i]
// then softmax over c -> coef[b][n][c]; store b_new -> blog[b][n][c].
template <bool ADD_B>
__global__ __launch_bounds__(256) void k_route(const float* __restrict__ x,
                                               const float* __restrict__ w,
                                               float* __restrict__ blog,
                                               float* __restrict__ coef) {
  int b = blockIdx.x;
  int n0 = blockIdx.y * 32;
  int tid = threadIdx.x;
  int wid = tid >> 6, lane = tid & 63;  // lane = capsule c

  __shared__ float w_lds[DI * NC];  // 64 KB

  const float* wb = w + b * (NC * DI);
  for (int idx = tid; idx < NC * DI; idx += 256) {
    int c = idx >> 8, i = idx & 255;
    w_lds[i * 64 + (c ^ (i & 63))] = wb[idx];
  }
  __syncthreads();

  float acc[8];
#pragma unroll
  for (int k = 0; k < 8; ++k) acc[k] = 0.f;

#pragma unroll 1
  for (int chunk = 0; chunk < 4; ++chunk) {
    int i0 = chunk * 64;
    float wreg[64];
#pragma unroll
    for (int j = 0; j < 64; ++j)
      wreg[j] = w_lds[(i0 + j) * 64 + (lane ^ j)];

#pragma unroll
    for (int k = 0; k < 8; ++k) {
      int n = n0 + wid * 8 + k;
      const float4* xp = (const float4*)(x + (b * NN + n) * DI + i0);
#pragma unroll
      for (int q = 0; q < 16; ++q) {
        float4 xv = xp[q];
        acc[k] += xv.x * wreg[q * 4 + 0] + xv.y * wreg[q * 4 + 1] +
                  xv.z * wreg[q * 4 + 2] + xv.w * wreg[q * 4 + 3];
      }
    }
  }

#pragma unroll 1
  for (int k = 0; k < 8; ++k) {
    int n = n0 + wid * 8 + k;
    float v = acc[k];
    if (ADD_B) v += blog[(b * NN + n) * NC + lane];
    blog[(b * NN + n) * NC + lane] = v;
    float m = v;
#pragma unroll
    for (int off = 32; off >= 1; off >>= 1) m = fmaxf(m, __shfl_xor(m, off, 64));
    float e = __expf(v - m);
    float s = e;
#pragma unroll
    for (int off = 32; off >= 1; off >>= 1) s += __shfl_xor(s, off, 64);
    coef[(b * NN + n) * NC + lane] = e / s;
  }
}

// ---------------------------------------------------------------------------
// y[b,c,i] = sum_n coef[b][n][c] * x[b][n][i].  Block: (b, 4-c group).
__global__ __launch_bounds__(256) void k_y(const float* __restrict__ x,
                                           const float* __restrict__ coef,
                                           float* __restrict__ y) {
  int b = blockIdx.x;
  int c0 = blockIdx.y * 4;
  int i = threadIdx.x;
  const float* xb = x + b * NN * DI;
  const float* cb = coef + b * NN * NC + c0;
  float a0 = 0.f, a1 = 0.f, a2 = 0.f, a3 = 0.f;
#pragma unroll 4
  for (int n = 0; n < NN; ++n) {
    float xv = xb[n * DI + i];
    float c0v = cb[n * NC + 0];
    float c1v = cb[n * NC + 1];
    float c2v = cb[n * NC + 2];
    float c3v = cb[n * NC + 3];
    a0 += xv * c0v; a1 += xv * c1v; a2 += xv * c2v; a3 += xv * c3v;
  }
  y[((b * NC) + c0 + 0) * DI + i] = a0;
  y[((b * NC) + c0 + 1) * DI + i] = a1;
  y[((b * NC) + c0 + 2) * DI + i] = a2;
  y[((b * NC) + c0 + 3) * DI + i] = a3;
}

// ---------------------------------------------------------------------------
extern "C" void kernel_launch(void* const* d_in, const int* in_sizes, int n_in,
                              void* d_out, int out_size, void* d_ws, size_t ws_size,
                              hipStream_t stream) {
  (void)in_sizes; (void)n_in; (void)out_size; (void)ws_size;
  const float* x    = (const float*)d_in[0];   // [16,512,256]
  const float* kern = (const float*)d_in[1];   // [256,8192]
  float* out = (float*)d_out;                  // [16,64,128]

  float* part = (float*)d_ws;                  // 16*16*256   = 65536 f
  float* xsum = part + NB * 16 * DI;           // 16*256      = 4096 f
  float* y    = xsum + NB * DI;                // 16*64*256   = 262144 f
  float* w    = y + NB * NC * DI;              // 16*64*256   = 262144 f
  float* blog = w + NB * NC * DI;              // 16*512*64   = 524288 f
  float* coef = blog + NB * NN * NC;           // 16*512*64   = 524288 f

  k_part<<<dim3(NB, 16), 256, 0, stream>>>(x, part);
  k_xsum<<<NB, 256, 0, stream>>>(part, xsum);

  // iteration 0: c uniform = 1/64 -> o0, w0
  k_o2<true, true, false><<<dim3(NC, 2), 256, 0, stream>>>(kern, y, xsum, w, out);
  k_route<false><<<dim3(NB, 16), 256, 0, stream>>>(x, w, blog, coef);

  // iteration 1
  k_y<<<dim3(NB, 16), 256, 0, stream>>>(x, coef, y);
  k_o2<false, true, false><<<dim3(NC, 2), 256, 0, stream>>>(kern, y, xsum, w, out);
  k_route<true><<<dim3(NB, 16), 256, 0, stream>>>(x, w, blog, coef);

  // iteration 2 (final): o2 -> out
  k_y<<<dim3(NB, 16), 256, 0, stream>>>(x, coef, y);
  k_o2<false, false, true><<<dim3(NC, 2), 256, 0, stream>>>(kern, y, xsum, w, out);
}

// Round 3
// 128.592 us; speedup vs baseline: 1.6468x; 1.0572x over previous
//
#include <hip/hip_runtime.h>

#define NB 16   // batch
#define NN 512  // input capsules (n)
#define DI 256  // input dim (i)
#define NC 64   // output capsules (c)
#define ND 128  // capsule dim (d)
#define FO 8192 // NC*DC

// ---------------------------------------------------------------------------
// Stage 1: column sums of x  (deterministic two-stage, no atomics)
__global__ __launch_bounds__(256) void k_part(const float* __restrict__ x,
                                              float* __restrict__ part) {
  int b = blockIdx.x, s = blockIdx.y, i = threadIdx.x;
  const float* xp = x + (b * NN + s * 32) * DI + i;
  float acc = 0.f;
#pragma unroll 8
  for (int n = 0; n < 32; ++n) acc += xp[n * DI];
  part[(b * 16 + s) * DI + i] = acc;
}

__global__ __launch_bounds__(256) void k_xsum(const float* __restrict__ part,
                                              float* __restrict__ xsum) {
  int b = blockIdx.x, i = threadIdx.x;
  float acc = 0.f;
#pragma unroll
  for (int s = 0; s < 16; ++s) acc += part[(b * 16 + s) * DI + i];
  xsum[b * DI + i] = acc;
}

// ---------------------------------------------------------------------------
// k_o2: per block = (c, half-of-batch). Computes for 8 b's:
//   O_raw[8,128] = Y[8,256] . Kc[256,128]; O = squash(O_raw)
//   W[8,256] = O[8,128] . Kc^T              (if CALC_W)
template <bool FIRST, bool CALC_W, bool TO_OUT>
__global__ __launch_bounds__(256) void k_o2(const float* __restrict__ kern,
                                            const float* __restrict__ yb,
                                            const float* __restrict__ xsum,
                                            float* __restrict__ wout,
                                            float* __restrict__ outp) {
  int c = blockIdx.x;        // 0..63
  int b0 = blockIdx.y * 8;   // 0 or 8
  int tid = threadIdx.x;

  __shared__ float y_lds[8][256];   // 8 KB
  __shared__ float u_lds[8192];     // 32 KB
  __shared__ float o_lds[8][128];   // 4 KB

#pragma unroll
  for (int k = 0; k < 2; ++k) {
    int e4 = tid + k * 256;
    int bb = e4 >> 6, i4 = e4 & 63;
    float4 v;
    if (FIRST) {
      v = ((const float4*)xsum)[(b0 + bb) * 64 + i4];
      v.x *= (1.f / 64.f); v.y *= (1.f / 64.f); v.z *= (1.f / 64.f); v.w *= (1.f / 64.f);
    } else {
      v = ((const float4*)yb)[((b0 + bb) * 64 + c) * 64 + i4];
    }
    ((float4*)&y_lds[bb][0])[i4] = v;
  }
  __syncthreads();

  // phase 1: partial O_raw. thread = (i-half 0..7, d-quad 0..31)
  {
    int dq = tid & 31;
    int half = tid >> 5;
    float4 acc[8];
#pragma unroll
    for (int bb = 0; bb < 8; ++bb) { acc[bb].x = acc[bb].y = acc[bb].z = acc[bb].w = 0.f; }
    const float* kp = kern + c * ND + dq * 4;
#pragma unroll 4
    for (int t = 0; t < 32; ++t) {
      int i = half * 32 + t;
      float4 kv = *(const float4*)(kp + (size_t)i * FO);
#pragma unroll
      for (int bb = 0; bb < 8; ++bb) {
        float yv = y_lds[bb][i];
        acc[bb].x += yv * kv.x; acc[bb].y += yv * kv.y;
        acc[bb].z += yv * kv.z; acc[bb].w += yv * kv.w;
      }
    }
    float4* p4 = (float4*)u_lds;
#pragma unroll
    for (int bb = 0; bb < 8; ++bb) p4[(half * 8 + bb) * 32 + dq] = acc[bb];
  }
  __syncthreads();

  // combine partials + squash. thread = (bb 0..7, j 0..31)
  {
    int bb = tid >> 5, j = tid & 31;
    const float4* p4 = (const float4*)u_lds;
    float4 o; o.x = o.y = o.z = o.w = 0.f;
#pragma unroll
    for (int h = 0; h < 8; ++h) {
      float4 p = p4[(h * 8 + bb) * 32 + j];
      o.x += p.x; o.y += p.y; o.z += p.z; o.w += p.w;
    }
    float sq = o.x * o.x + o.y * o.y + o.z * o.z + o.w * o.w;
#pragma unroll
    for (int off = 16; off >= 1; off >>= 1) sq += __shfl_xor(sq, off, 64);
    float tot = sq + 1e-7f;
    float scale = sqrtf(tot) / (0.5f + tot);
    o.x *= scale; o.y *= scale; o.z *= scale; o.w *= scale;
    ((float4*)&o_lds[bb][0])[j] = o;
    if (TO_OUT) ((float4*)outp)[((b0 + bb) * NC + c) * 32 + j] = o;
  }
  __syncthreads();

  // phase 2: W[8,256] = O . Kc^T, i-tiles of 32 staged in LDS
  if (CALC_W) {
    float* kt = u_lds;   // [32][132]
    int bb = tid >> 5, ii = tid & 31;
    const float4* o4 = (const float4*)&o_lds[bb][0];
#pragma unroll 1
    for (int i0 = 0; i0 < DI; i0 += 32) {
#pragma unroll
      for (int k = 0; k < 4; ++k) {
        int e4 = tid + k * 256;
        int r = e4 >> 5, q = e4 & 31;
        float4 v = *(const float4*)(kern + (size_t)(i0 + r) * FO + c * ND + q * 4);
        *(float4*)(kt + r * 132 + q * 4) = v;
      }
      __syncthreads();
      float wacc = 0.f;
#pragma unroll 8
      for (int q = 0; q < 32; ++q) {
        float4 kv = *(const float4*)(kt + ii * 132 + q * 4);
        float4 ov = o4[q];
        wacc += kv.x * ov.x + kv.y * ov.y + kv.z * ov.z + kv.w * ov.w;
      }
      wout[((b0 + bb) * NC + c) * DI + i0 + ii] = wacc;
      __syncthreads();
    }
  }
}

// ---------------------------------------------------------------------------
// routing update: b_new[b,c,n] = (ADD_B ? b_old : 0) + sum_i x[b,n,i]*w[b,c,i]
// then softmax over c -> coef[b][n][c]; store b_new -> blog[b][n][c].
// Block = (b, 16-n tile). 256 threads = 4 waves; lane = c; wave owns 4 n.
// x-tile staged in LDS (16 KB); w staged in 64-i chunks [64][64] XOR-swizzled,
// double-buffered (2x16 KB) with register prefetch. Inner loop is LDS+FMA only.
template <bool ADD_B>
__global__ __launch_bounds__(256) void k_route(const float* __restrict__ x,
                                               const float* __restrict__ w,
                                               float* __restrict__ blog,
                                               float* __restrict__ coef) {
  int b = blockIdx.x;
  int n0 = blockIdx.y * 16;
  int tid = threadIdx.x;
  int wid = tid >> 6, lane = tid & 63;  // lane = capsule c

  __shared__ float x_lds[16][256];      // 16 KB
  __shared__ float wch[2][64 * 64];     // 2 x 16 KB, [j][c ^ j]

  // stage x-tile (coalesced float4)
#pragma unroll
  for (int k = 0; k < 4; ++k) {
    int e4 = tid + k * 256;            // 0..1023
    int r = e4 >> 6, q = e4 & 63;
    ((float4*)&x_lds[r][0])[q] =
        ((const float4*)(x + (size_t)(b * NN + n0 + r) * DI))[q];
  }

  // stage-load indices for w chunks: thread covers c = tid>>4? no:
  // e4 = tid + k*256 -> c = e4>>4 (0..63), iq = e4&15 (float4 along i)
  const float* wb = w + (size_t)b * NC * DI;

  // prologue: chunk 0 -> wch[0]
  {
#pragma unroll
    for (int k = 0; k < 4; ++k) {
      int e4 = tid + k * 256;
      int c = e4 >> 4, iq = e4 & 15;
      float4 v = *(const float4*)(wb + (size_t)c * DI + iq * 4);
      int j0 = iq * 4;
      wch[0][(j0 + 0) * 64 + (c ^ (j0 + 0))] = v.x;
      wch[0][(j0 + 1) * 64 + (c ^ (j0 + 1))] = v.y;
      wch[0][(j0 + 2) * 64 + (c ^ (j0 + 2))] = v.z;
      wch[0][(j0 + 3) * 64 + (c ^ (j0 + 3))] = v.w;
    }
  }
  __syncthreads();

  float acc[4];
#pragma unroll
  for (int k = 0; k < 4; ++k) acc[k] = 0.f;

#pragma unroll 1
  for (int chunk = 0; chunk < 4; ++chunk) {
    int cur = chunk & 1;
    // prefetch next chunk into registers (issues early, lands during FMA)
    float4 pre[4];
    if (chunk < 3) {
#pragma unroll
      for (int k = 0; k < 4; ++k) {
        int e4 = tid + k * 256;
        int c = e4 >> 4, iq = e4 & 15;
        pre[k] = *(const float4*)(wb + (size_t)c * DI + (chunk + 1) * 64 + iq * 4);
      }
    }

    // wreg fill (conflict-free: lane^j permutation per row)
    float wreg[64];
#pragma unroll
    for (int j = 0; j < 64; ++j) wreg[j] = wch[cur][j * 64 + (lane ^ j)];

    // FMA: wave wid owns n = n0 + wid*4 .. +3; x reads are wave-uniform bcast
#pragma unroll
    for (int nn = 0; nn < 4; ++nn) {
      const float4* xr = (const float4*)&x_lds[wid * 4 + nn][chunk * 64];
#pragma unroll
      for (int q = 0; q < 16; ++q) {
        float4 xv = xr[q];
        acc[nn] += xv.x * wreg[q * 4 + 0] + xv.y * wreg[q * 4 + 1] +
                   xv.z * wreg[q * 4 + 2] + xv.w * wreg[q * 4 + 3];
      }
    }

    if (chunk < 3) {
      int nxt = 1 - cur;
#pragma unroll
      for (int k = 0; k < 4; ++k) {
        int e4 = tid + k * 256;
        int c = e4 >> 4, iq = e4 & 15;
        int j0 = iq * 4;
        wch[nxt][(j0 + 0) * 64 + (c ^ (j0 + 0))] = pre[k].x;
        wch[nxt][(j0 + 1) * 64 + (c ^ (j0 + 1))] = pre[k].y;
        wch[nxt][(j0 + 2) * 64 + (c ^ (j0 + 2))] = pre[k].z;
        wch[nxt][(j0 + 3) * 64 + (c ^ (j0 + 3))] = pre[k].w;
      }
      __syncthreads();
    }
  }

  // add old logits, store, softmax over c (= lanes)
#pragma unroll
  for (int nn = 0; nn < 4; ++nn) {
    int n = n0 + wid * 4 + nn;
    float v = acc[nn];
    if (ADD_B) v += blog[(size_t)(b * NN + n) * NC + lane];
    blog[(size_t)(b * NN + n) * NC + lane] = v;
    float m = v;
#pragma unroll
    for (int off = 32; off >= 1; off >>= 1) m = fmaxf(m, __shfl_xor(m, off, 64));
    float e = __expf(v - m);
    float s = e;
#pragma unroll
    for (int off = 32; off >= 1; off >>= 1) s += __shfl_xor(s, off, 64);
    coef[(size_t)(b * NN + n) * NC + lane] = e / s;
  }
}

// ---------------------------------------------------------------------------
// y[b,c,i] = sum_n coef[b][n][c] * x[b][n][i].  Block: (b, 4-c group).
// 512 threads: half = tid>>8 owns one n-half of 256; LDS combine.
__global__ __launch_bounds__(512) void k_y(const float* __restrict__ x,
                                           const float* __restrict__ coef,
                                           float* __restrict__ y) {
  int b = blockIdx.x;
  int c0 = blockIdx.y * 4;
  int tid = threadIdx.x;
  int i = tid & 255, half = tid >> 8;

  __shared__ float part_lds[4][256];

  const float* xb = x + (size_t)b * NN * DI + (size_t)half * 256 * DI;
  const float* cb = coef + (size_t)b * NN * NC + (size_t)half * 256 * NC + c0;
  float a0 = 0.f, a1 = 0.f, a2 = 0.f, a3 = 0.f;
#pragma unroll 4
  for (int n = 0; n < 256; ++n) {
    float xv = xb[n * DI + i];
    float c0v = cb[n * NC + 0];
    float c1v = cb[n * NC + 1];
    float c2v = cb[n * NC + 2];
    float c3v = cb[n * NC + 3];
    a0 += xv * c0v; a1 += xv * c1v; a2 += xv * c2v; a3 += xv * c3v;
  }
  if (half == 1) {
    part_lds[0][i] = a0; part_lds[1][i] = a1;
    part_lds[2][i] = a2; part_lds[3][i] = a3;
  }
  __syncthreads();
  if (half == 0) {
    y[((size_t)(b * NC) + c0 + 0) * DI + i] = a0 + part_lds[0][i];
    y[((size_t)(b * NC) + c0 + 1) * DI + i] = a1 + part_lds[1][i];
    y[((size_t)(b * NC) + c0 + 2) * DI + i] = a2 + part_lds[2][i];
    y[((size_t)(b * NC) + c0 + 3) * DI + i] = a3 + part_lds[3][i];
  }
}

// ---------------------------------------------------------------------------
extern "C" void kernel_launch(void* const* d_in, const int* in_sizes, int n_in,
                              void* d_out, int out_size, void* d_ws, size_t ws_size,
                              hipStream_t stream) {
  (void)in_sizes; (void)n_in; (void)out_size; (void)ws_size;
  const float* x    = (const float*)d_in[0];   // [16,512,256]
  const float* kern = (const float*)d_in[1];   // [256,8192]
  float* out = (float*)d_out;                  // [16,64,128]

  float* part = (float*)d_ws;                  // 16*16*256   = 65536 f
  float* xsum = part + NB * 16 * DI;           // 16*256      = 4096 f
  float* y    = xsum + NB * DI;                // 16*64*256   = 262144 f
  float* w    = y + NB * NC * DI;              // 16*64*256   = 262144 f
  float* blog = w + NB * NC * DI;              // 16*512*64   = 524288 f
  float* coef = blog + NB * NN * NC;           // 16*512*64   = 524288 f

  k_part<<<dim3(NB, 16), 256, 0, stream>>>(x, part);
  k_xsum<<<NB, 256, 0, stream>>>(part, xsum);

  // iteration 0: c uniform = 1/64 -> o0, w0
  k_o2<true, true, false><<<dim3(NC, 2), 256, 0, stream>>>(kern, y, xsum, w, out);
  k_route<false><<<dim3(NB, 32), 256, 0, stream>>>(x, w, blog, coef);

  // iteration 1
  k_y<<<dim3(NB, 16), 512, 0, stream>>>(x, coef, y);
  k_o2<false, true, false><<<dim3(NC, 2), 256, 0, stream>>>(kern, y, xsum, w, out);
  k_route<true><<<dim3(NB, 32), 256, 0, stream>>>(x, w, blog, coef);

  // iteration 2 (final): o2 -> out
  k_y<<<dim3(NB, 16), 512, 0, stream>>>(x, coef, y);
  k_o2<false, false, true><<<dim3(NC, 2), 256, 0, stream>>>(kern, y, xsum, w, out);
}